// Round 10
// baseline (74.571 us; speedup 1.0000x reference)
//
#include <hip/hip_runtime.h>
#include <hip/hip_bf16.h>

typedef __attribute__((ext_vector_type(8))) short s16x8;   // 8 bf16 (4 VGPRs)
typedef __attribute__((ext_vector_type(4))) float f32x4;

#define NPTS    8192
#define GSIZE   16384
#define NHL2E   (-0.7213475204444817f)   // -0.5 * log2(e)
#define NSPLIT  32                       // K splits (KCH = 256 each)
#define NBLK    512                      // 4 mt x 4 iyt x 32 s

// ws layout (bytes): partials | Amat | Bmat
#define P_OFF   0                               // 512*3072*4 = 6.3 MB
#define A_OFF   ((size_t)NBLK * 3072 * 4)       // A: 128 x 8192 bf16 = 2 MB
#define B_OFF   (A_OFF + 128 * 8192 * 2)        // B: 384 x 8192 bf16 = 6 MB
#define WS_NEEDED (B_OFF + 384 * 8192 * 2)

__device__ __forceinline__ unsigned int pk2(float a, float b) {
    // v_cvt_pk_bf16_f32 (RNE): 1 instr packs 2 floats
    __hip_bfloat162 h = __float22bfloat162_rn(make_float2(a, b));
    unsigned int u;
    __builtin_memcpy(&u, &h, sizeof(u));
    return u;
}

// ---- K1: gen A[ix][j], B-stack[c*128+iy][j] — every exp computed ONCE ------
__global__ __launch_bounds__(256) void gen_kernel(
    const float* __restrict__ X, const float* __restrict__ Y,
    unsigned short* __restrict__ Amat, unsigned short* __restrict__ Bmat)
{
    const int b = blockIdx.x, tid = threadIdx.x;
    const float4* X4 = (const float4*)X;   // {xj0, xj1, x(j+1)0, x(j+1)1}
    const float4* Y4 = (const float4*)Y;
    if (b < 512) {                          // A-part: 128 rows x 4 blocks/row
        int ix = b >> 2;
        int j0 = (b & 3) * 2048 + tid * 8;
        float gx = -2.0f + (float)ix * (4.0f / 127.0f);
        float e[8];
        #pragma unroll
        for (int i = 0; i < 4; ++i) {
            float4 p = X4[(j0 >> 1) + i];
            float d0 = gx - p.x, d1 = gx - p.z;
            e[2*i]   = __builtin_amdgcn_exp2f(d0 * d0 * NHL2E);
            e[2*i+1] = __builtin_amdgcn_exp2f(d1 * d1 * NHL2E);
        }
        uint4 v;
        v.x = pk2(e[0], e[1]); v.y = pk2(e[2], e[3]);
        v.z = pk2(e[4], e[5]); v.w = pk2(e[6], e[7]);
        *(uint4*)(Amat + ix * NPTS + j0) = v;
    } else {                                // B-part: B0, B0*y0, B0*y1
        int bb = b - 512;
        int iy = bb >> 2;
        int j0 = (bb & 3) * 2048 + tid * 8;
        float gy = -2.0f + (float)iy * (4.0f / 127.0f);
        float e[8], w0[8], w1[8];
        #pragma unroll
        for (int i = 0; i < 4; ++i) {
            float4 p = X4[(j0 >> 1) + i];
            float4 q = Y4[(j0 >> 1) + i];
            float d0 = gy - p.y, d1 = gy - p.w;
            e[2*i]   = __builtin_amdgcn_exp2f(d0 * d0 * NHL2E);
            e[2*i+1] = __builtin_amdgcn_exp2f(d1 * d1 * NHL2E);
            w0[2*i] = q.x; w0[2*i+1] = q.z;
            w1[2*i] = q.y; w1[2*i+1] = q.w;
        }
        uint4 v0, v1, v2;
        v0.x = pk2(e[0], e[1]);             v0.y = pk2(e[2], e[3]);
        v0.z = pk2(e[4], e[5]);             v0.w = pk2(e[6], e[7]);
        v1.x = pk2(e[0]*w0[0], e[1]*w0[1]); v1.y = pk2(e[2]*w0[2], e[3]*w0[3]);
        v1.z = pk2(e[4]*w0[4], e[5]*w0[5]); v1.w = pk2(e[6]*w0[6], e[7]*w0[7]);
        v2.x = pk2(e[0]*w1[0], e[1]*w1[1]); v2.y = pk2(e[2]*w1[2], e[3]*w1[3]);
        v2.z = pk2(e[4]*w1[4], e[5]*w1[5]); v2.w = pk2(e[6]*w1[6], e[7]*w1[7]);
        *(uint4*)(Bmat + (iy)       * NPTS + j0) = v0;
        *(uint4*)(Bmat + (128 + iy) * NPTS + j0) = v1;
        *(uint4*)(Bmat + (256 + iy) * NPTS + j0) = v2;
    }
}

// ---- K2: MFMA GEMM, no LDS — direct global fragment loads (L2-resident) ----
// Tile = 32m x 32n x 256k per block; 4 waves = 2x2 quadrants of 16x16.
// A-frag: m=lane&15, k=quad*8+j; C/D: col(n)=lane&15, row(m)=quad*4+reg.
// Partials: block-contiguous [b][ch(3)][n(32)][m(32)] (identical to R9).
__global__ __launch_bounds__(256) void gemm_kernel(
    const unsigned short* __restrict__ Amat,
    const unsigned short* __restrict__ Bmat,
    float* __restrict__ part)
{
    const int tid = threadIdx.x;
    const int b   = blockIdx.x;            // 512 blocks
    const int s    = b & (NSPLIT - 1);
    const int rest = b >> 5;
    const int mt = rest & 3, iyt = rest >> 2;

    const int w = tid >> 6, lane = tid & 63;
    const int wm = w & 1, wn = w >> 1;
    const int r = lane & 15, quad = lane >> 4;

    const unsigned short* ap = Amat + (mt * 32 + wm * 16 + r) * NPTS
                               + s * 256 + quad * 8;
    const unsigned short* bp = Bmat + (iyt * 32 + wn * 16 + r) * NPTS
                               + s * 256 + quad * 8;

    f32x4 a0 = {0.f, 0.f, 0.f, 0.f}, a1 = a0, a2 = a0;
    #pragma unroll
    for (int kk = 0; kk < 256; kk += 32) {
        s16x8 a  = *(const s16x8*)(ap + kk);
        s16x8 b0 = *(const s16x8*)(bp + kk);
        s16x8 b1 = *(const s16x8*)(bp + 128 * NPTS + kk);
        s16x8 b2 = *(const s16x8*)(bp + 256 * NPTS + kk);
        a0 = __builtin_amdgcn_mfma_f32_16x16x32_bf16(a, b0, a0, 0, 0, 0);
        a1 = __builtin_amdgcn_mfma_f32_16x16x32_bf16(a, b1, a1, 0, 0, 0);
        a2 = __builtin_amdgcn_mfma_f32_16x16x32_bf16(a, b2, a2, 0, 0, 0);
    }

    float* dst = part + b * 3072;
    const int off = (wn * 16 + r) * 32 + wm * 16 + quad * 4;
    *(f32x4*)(dst + off)        = a0;
    *(f32x4*)(dst + 1024 + off) = a1;
    *(f32x4*)(dst + 2048 + off) = a2;
}

// ---- K3: 256 blocks x 256 thr; thread = (output, split-quarter); LDS combine
__global__ __launch_bounds__(256) void reduce32_kernel(
    const float* __restrict__ part, float* __restrict__ out)
{
    __shared__ float red[4][3][64];                 // 3 KB
    const int tid = threadIdx.x;
    const int ol = tid & 63, q = tid >> 6;
    const int o = blockIdx.x * 64 + ol;             // o = iy*128 + ix
    const int iy = o >> 7, ix = o & 127;
    const int iyt = iy >> 5, nl = iy & 31, mt = ix >> 5, ml = ix & 31;
    const float* p = part + (size_t)((iyt * 4 + mt) * 32 + q * 8) * 3072
                     + nl * 32 + ml;
    float f0 = 0.f, f1 = 0.f, f2 = 0.f;
    #pragma unroll
    for (int s = 0; s < 8; ++s) {                   // 24 independent loads
        const float* qp = p + s * 3072;
        f0 += qp[0]; f1 += qp[1024]; f2 += qp[2048];
    }
    red[q][0][ol] = f0; red[q][1][ol] = f1; red[q][2][ol] = f2;
    __syncthreads();
    if (tid < 64) {
        float g0 = red[0][0][tid] + red[1][0][tid] + red[2][0][tid] + red[3][0][tid];
        float g1 = red[0][1][tid] + red[1][1][tid] + red[2][1][tid] + red[3][1][tid];
        float g2 = red[0][2][tid] + red[1][2][tid] + red[2][2][tid] + red[3][2][tid];
        float inv = 1.0f / g0;
        int oo = blockIdx.x * 64 + tid;
        out[oo]          = g0;                      // denom: NOT divided
        out[16384 + oo]  = g1 * inv;
        out[32768 + oo]  = g2 * inv;
    }
}

// ---- Fallback: proven R1 single-kernel (if ws too small) -------------------
#define TS 1024
__global__ __launch_bounds__(256, 4) void convcnp_fallback(
    const float* __restrict__ X, const float* __restrict__ Y, float* __restrict__ out)
{
    __shared__ float4 tile[TS];
    const int tid = threadIdx.x;
    const int gq  = tid >> 4;
    const int sg  = tid & 15;
    const int gi = blockIdx.x * 16 + gq;
    const int ix = gi >> 7, iy = gi & 127;
    const float gx = -2.0f + (float)ix * (4.0f / 127.0f);
    const float gy = -2.0f + (float)iy * (4.0f / 127.0f);
    float s0 = 0.f, s1 = 0.f, s2 = 0.f;
    const float4* X4 = (const float4*)X;
    const float4* Y4 = (const float4*)Y;
    for (int t = 0; t < NPTS / TS; ++t) {
        #pragma unroll
        for (int i = 0; i < TS / 2; i += 256) {
            float4 xa = X4[t * (TS / 2) + i + tid];
            float4 ya = Y4[t * (TS / 2) + i + tid];
            int p = 2 * (i + tid);
            tile[p]     = make_float4(xa.x, xa.y, ya.x, ya.y);
            tile[p + 1] = make_float4(xa.z, xa.w, ya.z, ya.w);
        }
        __syncthreads();
        #pragma unroll 8
        for (int j = 0; j < TS / 16; ++j) {
            float4 p = tile[j * 16 + sg];
            float dx = gx - p.x, dy = gy - p.y;
            float k = __expf(-0.5f * (dx * dx + dy * dy));
            s0 += k; s1 += k * p.z; s2 += k * p.w;
        }
        __syncthreads();
    }
    #pragma unroll
    for (int off = 8; off >= 1; off >>= 1) {
        s0 += __shfl_down(s0, off, 16);
        s1 += __shfl_down(s1, off, 16);
        s2 += __shfl_down(s2, off, 16);
    }
    if (sg == 0) {
        const int o = iy * 128 + ix;
        float inv = 1.0f / s0;
        out[o] = s0; out[GSIZE + o] = s1 * inv; out[2 * GSIZE + o] = s2 * inv;
    }
}

extern "C" void kernel_launch(void* const* d_in, const int* in_sizes, int n_in,
                              void* d_out, int out_size, void* d_ws, size_t ws_size,
                              hipStream_t stream) {
    const float* X = (const float*)d_in[0];
    const float* Y = (const float*)d_in[1];
    float* out = (float*)d_out;
    if (ws_size >= WS_NEEDED) {
        float* part = (float*)((char*)d_ws + P_OFF);
        unsigned short* Amat = (unsigned short*)((char*)d_ws + A_OFF);
        unsigned short* Bmat = (unsigned short*)((char*)d_ws + B_OFF);
        gen_kernel<<<1024, 256, 0, stream>>>(X, Y, Amat, Bmat);
        gemm_kernel<<<NBLK, 256, 0, stream>>>(Amat, Bmat, part);
        reduce32_kernel<<<GSIZE / 64, 256, 0, stream>>>(part, out);
    } else {
        convcnp_fallback<<<GSIZE / 16, 256, 0, stream>>>(X, Y, out);
    }
}